// Round 7
// baseline (852.792 us; speedup 1.0000x reference)
//
#include <hip/hip_runtime.h>

#define L_ 2048
#define H_ 8

typedef __attribute__((ext_vector_type(8))) short short8;
typedef __attribute__((ext_vector_type(4))) float f32x4;

static constexpr size_t OFF_S = 2097152;            // B*L*H*D
static constexpr size_t OFF_P = OFF_S + 67108864;   // + B*H*L*L
static constexpr size_t OFF_G = OFF_P + 67108864;

// ws layout (bytes): K tiles at 1 MB (4 MB), V tiles at 5 MB (4 MB)
static constexpr size_t WS_K = 1u << 20;
static constexpr size_t WS_V = WS_K + (4u << 20);

__device__ __forceinline__ unsigned short f2bf(float x) {
    union { float f; unsigned int u; } c; c.f = x;
    unsigned int u = c.u;
    u += 0x7fffu + ((u >> 16) & 1u);               // RNE
    return (unsigned short)(u >> 16);
}

__device__ __forceinline__ void gld_lds16(const unsigned short* g, unsigned short* l) {
    __builtin_amdgcn_global_load_lds(
        (const __attribute__((address_space(1))) void*)g,
        (__attribute__((address_space(3))) void*)l, 16, 0, 0);
}

// non-temporal stores (native clang vector types required by the builtin)
__device__ __forceinline__ void st_nt4(float* p, f32x4 v) {
    __builtin_nontemporal_store(v, reinterpret_cast<f32x4*>(p));
}
__device__ __forceinline__ void st_nt1(float* p, float v) {
    __builtin_nontemporal_store(v, p);
}

// ===== kernel 0: K -> bf16 swizzled tiles; V -> bf16 transposed swizzled tiles =====
// tile image: 64 rows x 64 bf16; element (r, chunk c) at r*64 + (c ^ (r&7))*8 shorts.
__global__ __launch_bounds__(256) void prep(
    const float* __restrict__ k, const float* __restrict__ v,
    unsigned short* __restrict__ wsK, unsigned short* __restrict__ wsV)
{
    const int tid = threadIdx.x;
    const int blk = blockIdx.x;
    __shared__ __attribute__((aligned(16))) unsigned short tr[64][72];
    if (blk < 512) {                                 // K path: (bh, t)
        const int bh = blk >> 5, t = blk & 31;
        const int b = bh >> 3, h = bh & 7;
        unsigned short* dst = wsK + (size_t)(bh * 32 + t) * 4096;
        #pragma unroll
        for (int p = 0; p < 2; ++p) {
            const int cid = tid + (p << 8);
            const int r = cid >> 3, c = cid & 7;
            const int j = (t << 6) + r;
            const float4* src = reinterpret_cast<const float4*>(
                k + (((size_t)((b * L_ + j) * H_ + h)) << 6) + (c << 3));
            float4 x0 = src[0], x1 = src[1];
            union { short8 s; unsigned short u[8]; } w;
            w.u[0]=f2bf(x0.x); w.u[1]=f2bf(x0.y); w.u[2]=f2bf(x0.z); w.u[3]=f2bf(x0.w);
            w.u[4]=f2bf(x1.x); w.u[5]=f2bf(x1.y); w.u[6]=f2bf(x1.z); w.u[7]=f2bf(x1.w);
            *reinterpret_cast<short8*>(dst + r * 64 + ((c ^ (r & 7)) << 3)) = w.s;
        }
    } else {                                         // V path: transpose via LDS
        const int vb = blk - 512;
        const int bh = vb >> 5, t = vb & 31;
        const int b = bh >> 3, h = bh & 7;
        const int col4 = (tid & 15) << 2;
        #pragma unroll
        for (int p = 0; p < 4; ++p) {
            const int r = (tid >> 4) + (p << 4);
            const int j = (t << 6) + r;
            float4 x = *reinterpret_cast<const float4*>(
                v + (((size_t)((b * L_ + j) * H_ + h)) << 6) + col4);
            tr[col4 + 0][r] = f2bf(x.x); tr[col4 + 1][r] = f2bf(x.y);
            tr[col4 + 2][r] = f2bf(x.z); tr[col4 + 3][r] = f2bf(x.w);
        }
        __syncthreads();
        unsigned short* dst = wsV + (size_t)(bh * 32 + t) * 4096;
        #pragma unroll
        for (int p = 0; p < 2; ++p) {
            const int cid = tid + (p << 8);
            const int d = cid >> 3, cj = cid & 7;
            short8 s = *reinterpret_cast<const short8*>(&tr[d][cj << 3]);
            *reinterpret_cast<short8*>(dst + d * 64 + ((cj ^ (d & 7)) << 3)) = s;
        }
    }
}

// ===== kernel 1: fused attention, QBLK=32 (1024 blocks, whole grid co-resident) =====
// Phase 1: LDS-staged QK->exp->PV; one 16KB K/V tile now feeds 32 Q-rows
//          (staging traffic + barriers per unit work halved vs QBLK=16).
// Phase 2: MFMA recompute; normalized P bounced through DOUBLE-BUFFERED f32 LDS
//          tiles (idle Kb / Vb) -> 1 barrier per tile; every store = 256 B/row,
//          non-temporal.
__global__ __launch_bounds__(256, 4) void fused(
    const float* __restrict__ q, const float* __restrict__ sg,
    const unsigned short* __restrict__ wsK, const unsigned short* __restrict__ wsV,
    float* __restrict__ out)
{
    __shared__ __attribute__((aligned(16))) unsigned short Kb[2][4096];
    __shared__ __attribute__((aligned(16))) unsigned short Vb[2][4096];
    __shared__ __attribute__((aligned(16))) unsigned short Pt[32][72];
    __shared__ float l_sums[32];
    __shared__ float sA[32], sC2[32], sS[32];

    const int tid  = threadIdx.x;
    const int wv   = tid >> 6;
    const int lane = tid & 63;
    const int quad = lane >> 4;
    const int l16  = lane & 15;

    const int blk = blockIdx.x;
    const int s   = 63 - (blk >> 4);                 // heavy strips first
    const int bh  = blk & 15;
    const int b   = bh >> 3, h = bh & 7;
    const int i0  = s << 5;                          // 32-row strip

    const int ntiles = (s >> 1) + 1;
    const unsigned short* gK = wsK + ((size_t)bh * 32) * 4096;
    const unsigned short* gV = wsV + ((size_t)bh * 32) * 4096;

    #define STAGE(buf, t) do {                                              \
        const unsigned short* _sk = gK + (size_t)(t) * 4096;                \
        const unsigned short* _sv = gV + (size_t)(t) * 4096;                \
        _Pragma("unroll")                                                   \
        for (int _qq = 0; _qq < 2; ++_qq) {                                 \
            const int _off = (wv << 10) + (_qq << 9);                       \
            gld_lds16(_sk + _off + (lane << 3), &Kb[buf][_off]);            \
            gld_lds16(_sv + _off + (lane << 3), &Vb[buf][_off]);            \
        }                                                                   \
    } while (0)

    STAGE(0, 0);                                     // issue first DMA ASAP

    // sigma-derived per-row params (32 rows)
    if (tid < 32) {
        l_sums[tid] = 0.0f;
        const int i = i0 + tid;
        const float x = sg[(size_t)((b * L_ + i) * H_ + h)];
        const float sgm = 1.0f / (1.0f + __expf(-5.0f * x)) + 1e-5f;
        const float sp  = expm1f(sgm * 1.0986122886681098f);   // 3^sgm - 1
        sS[tid]  = sp;
        sA[tid]  = 0.3989422804014327f / sp;
        sC2[tid] = 0.5f / (sp * sp);
    }

    // Q A-fragments for both 16-row halves (fp32 -> bf16, once per block)
    short8 a0[2], a1[2];
    #pragma unroll
    for (int qh = 0; qh < 2; ++qh) {
        const float* qr = q + (((size_t)((b * L_ + (i0 + (qh << 4) + l16)) * H_ + h)) << 6);
        const float4* q4 = reinterpret_cast<const float4*>(qr) + quad * 2;
        float4 x0 = q4[0], x1 = q4[1];
        float4 y0 = q4[8], y1 = q4[9];
        union { short8 v8; unsigned short u[8]; } fa, fb;
        fa.u[0]=f2bf(x0.x); fa.u[1]=f2bf(x0.y); fa.u[2]=f2bf(x0.z); fa.u[3]=f2bf(x0.w);
        fa.u[4]=f2bf(x1.x); fa.u[5]=f2bf(x1.y); fa.u[6]=f2bf(x1.z); fa.u[7]=f2bf(x1.w);
        fb.u[0]=f2bf(y0.x); fb.u[1]=f2bf(y0.y); fb.u[2]=f2bf(y0.z); fb.u[3]=f2bf(y0.w);
        fb.u[4]=f2bf(y1.x); fb.u[5]=f2bf(y1.y); fb.u[6]=f2bf(y1.z); fb.u[7]=f2bf(y1.w);
        a0[qh] = fa.v8; a1[qh] = fb.v8;
    }

    f32x4 oacc[2] = {{0.f,0.f,0.f,0.f}, {0.f,0.f,0.f,0.f}};
    float lpart[2][4] = {{0.f,0.f,0.f,0.f}, {0.f,0.f,0.f,0.f}};
    const int r = (wv << 4) + l16;                   // K/V tile row this lane fragments

    for (int t = 0; t < ntiles; ++t) {
        const int p = t & 1;
        __syncthreads();                             // buf[p] staged; prev iter fully done
        if (t + 1 < ntiles) STAGE(1 - p, t + 1);     // overlap next DMA with compute
        short8 b0 = *reinterpret_cast<const short8*>(&Kb[p][r * 64 + ((quad ^ (r & 7)) << 3)]);
        short8 b1 = *reinterpret_cast<const short8*>(&Kb[p][r * 64 + (((quad + 4) ^ (r & 7)) << 3)]);
        const int j = (t << 6) + r;
        #pragma unroll
        for (int qh = 0; qh < 2; ++qh) {
            f32x4 c4 = {0.f, 0.f, 0.f, 0.f};
            c4 = __builtin_amdgcn_mfma_f32_16x16x32_bf16(a0[qh], b0, c4, 0, 0, 0);
            c4 = __builtin_amdgcn_mfma_f32_16x16x32_bf16(a1[qh], b1, c4, 0, 0, 0);
            #pragma unroll
            for (int rr = 0; rr < 4; ++rr) {
                const int i = i0 + (qh << 4) + (quad << 2) + rr;
                float pv = (j <= i) ? __expf(c4[rr] * 0.125f - 8.0f) : 0.0f;
                lpart[qh][rr] += pv;
                Pt[(qh << 4) + (quad << 2) + rr][r] = f2bf(pv);
            }
        }
        __syncthreads();
        short8 vb0 = *reinterpret_cast<const short8*>(&Vb[p][r * 64 + ((quad ^ (r & 7)) << 3)]);
        short8 vb1 = *reinterpret_cast<const short8*>(&Vb[p][r * 64 + (((quad + 4) ^ (r & 7)) << 3)]);
        #pragma unroll
        for (int qh = 0; qh < 2; ++qh) {
            short8 pa0 = *reinterpret_cast<const short8*>(&Pt[(qh << 4) + l16][quad << 3]);
            short8 pa1 = *reinterpret_cast<const short8*>(&Pt[(qh << 4) + l16][32 + (quad << 3)]);
            oacc[qh] = __builtin_amdgcn_mfma_f32_16x16x32_bf16(pa0, vb0, oacc[qh], 0, 0, 0);
            oacc[qh] = __builtin_amdgcn_mfma_f32_16x16x32_bf16(pa1, vb1, oacc[qh], 0, 0, 0);
        }
    }
    #undef STAGE

    #pragma unroll
    for (int qh = 0; qh < 2; ++qh)
    #pragma unroll
    for (int rr = 0; rr < 4; ++rr) {
        float x = lpart[qh][rr];
        x += __shfl_xor(x, 1); x += __shfl_xor(x, 2);
        x += __shfl_xor(x, 4); x += __shfl_xor(x, 8);
        if (l16 == 0) atomicAdd(&l_sums[(qh << 4) + (quad << 2) + rr], x);
    }
    __syncthreads();                                 // l_sums final; phase-1 LDS reads done

    float inv[2][4];
    #pragma unroll
    for (int qh = 0; qh < 2; ++qh)
    #pragma unroll
    for (int rr = 0; rr < 4; ++rr) {
        inv[qh][rr] = 1.0f / l_sums[(qh << 4) + (quad << 2) + rr];
        const int i = i0 + (qh << 4) + (quad << 2) + rr;
        st_nt1(out + (((size_t)((b * L_ + i) * H_ + h)) << 6) + (wv << 4) + l16,
               oacc[qh][rr] * inv[qh][rr]);
    }

    // ===== phase 2: streaming writeback, double-buffered LDS bounce =====
    float* outS = out + OFF_S;
    float* outP = out + OFF_P;
    float* outG = out + OFF_G;
    float* PsA = reinterpret_cast<float*>(&Kb[0][0]); // 32 x 68 f32 = 8704 B (within Kb's 16 KB)
    float* PsB = reinterpret_cast<float*>(&Vb[0][0]);

    // consumer lane map: pass p covers rows p*16 + wv*4 + quad, cols l16*4
    const int rc0  = (wv << 2) + quad;
    const int colc = l16 << 2;
    float Ac[2], C2c[2], fic[2];
    f32x4 svc[2];
    size_t rowbase[2];
    #pragma unroll
    for (int ps = 0; ps < 2; ++ps) {
        const int row = rc0 + (ps << 4);
        Ac[ps]  = sA[row]; C2c[ps] = sC2[row];
        const float Sv = sS[row];
        svc[ps] = (f32x4){Sv, Sv, Sv, Sv};
        fic[ps] = (float)(i0 + row);
        rowbase[ps] = ((size_t)(bh * L_ + i0 + row)) << 11;
    }

    // producer K-fragment offsets inside a tile (shorts) — same r as phase 1
    const int off0 = r * 64 + ((quad ^ (r & 7)) << 3);
    const int off1 = r * 64 + (((quad + 4) ^ (r & 7)) << 3);

    short8 kb0 = *reinterpret_cast<const short8*>(gK + off0);
    short8 kb1 = *reinterpret_cast<const short8*>(gK + off1);
    int t = 0;
    for (; t < ntiles; ++t) {
        short8 kn0 = kb0, kn1 = kb1;
        if (t + 1 < ntiles) {                        // reg prefetch: next tile's frags
            const unsigned short* kp = gK + (((size_t)(t + 1)) << 12);
            kn0 = *reinterpret_cast<const short8*>(kp + off0);
            kn1 = *reinterpret_cast<const short8*>(kp + off1);
        }
        float* Ps = (t & 1) ? PsB : PsA;
        const int j = (t << 6) + r;
        #pragma unroll
        for (int qh = 0; qh < 2; ++qh) {
            f32x4 c4 = {0.f, 0.f, 0.f, 0.f};
            c4 = __builtin_amdgcn_mfma_f32_16x16x32_bf16(a0[qh], kb0, c4, 0, 0, 0);
            c4 = __builtin_amdgcn_mfma_f32_16x16x32_bf16(a1[qh], kb1, c4, 0, 0, 0);
            #pragma unroll
            for (int rr = 0; rr < 4; ++rr) {
                const int i = i0 + (qh << 4) + (quad << 2) + rr;
                const float pv = (j <= i) ? __expf(c4[rr] * 0.125f - 8.0f) * inv[qh][rr] : 0.0f;
                Ps[((qh << 4) + (quad << 2) + rr) * 68 + r] = pv;
            }
        }
        asm volatile("s_waitcnt lgkmcnt(0)" ::: "memory");
        __builtin_amdgcn_sched_barrier(0);
        __builtin_amdgcn_s_barrier();                // P tile visible; single barrier/iter
        #pragma unroll
        for (int ps = 0; ps < 2; ++ps) {
            const f32x4 se = *reinterpret_cast<const f32x4*>(&Ps[(rc0 + (ps << 4)) * 68 + colc]);
            const int c = (t << 6) + colc;
            const float d0 = fic[ps] - (float)c;
            const float d1 = d0 - 1.f, d2 = d0 - 2.f, d3 = d0 - 3.f;
            f32x4 pr;
            pr.x = Ac[ps] * __expf(-d0 * d0 * C2c[ps]);
            pr.y = Ac[ps] * __expf(-d1 * d1 * C2c[ps]);
            pr.z = Ac[ps] * __expf(-d2 * d2 * C2c[ps]);
            pr.w = Ac[ps] * __expf(-d3 * d3 * C2c[ps]);
            st_nt4(outS + rowbase[ps] + c, se);
            st_nt4(outP + rowbase[ps] + c, pr);
            st_nt4(outG + rowbase[ps] + c, svc[ps]);
        }
        kb0 = kn0; kb1 = kn1;
    }
    const f32x4 z4 = {0.f, 0.f, 0.f, 0.f};
    for (; t < 32; ++t) {                            // pure streaming: zeros + prior + sigma
        #pragma unroll
        for (int ps = 0; ps < 2; ++ps) {
            const int c = (t << 6) + colc;
            const float d0 = fic[ps] - (float)c;
            const float d1 = d0 - 1.f, d2 = d0 - 2.f, d3 = d0 - 3.f;
            f32x4 pr;
            pr.x = Ac[ps] * __expf(-d0 * d0 * C2c[ps]);
            pr.y = Ac[ps] * __expf(-d1 * d1 * C2c[ps]);
            pr.z = Ac[ps] * __expf(-d2 * d2 * C2c[ps]);
            pr.w = Ac[ps] * __expf(-d3 * d3 * C2c[ps]);
            st_nt4(outS + rowbase[ps] + c, z4);
            st_nt4(outP + rowbase[ps] + c, pr);
            st_nt4(outG + rowbase[ps] + c, svc[ps]);
        }
    }
}

extern "C" void kernel_launch(void* const* d_in, const int* in_sizes, int n_in,
                              void* d_out, int out_size, void* d_ws, size_t ws_size,
                              hipStream_t stream) {
    const float* q  = (const float*)d_in[0];
    const float* k  = (const float*)d_in[1];
    const float* v  = (const float*)d_in[2];
    const float* sg = (const float*)d_in[3];
    float* outp = (float*)d_out;
    unsigned short* wsK = (unsigned short*)((char*)d_ws + WS_K);
    unsigned short* wsV = (unsigned short*)((char*)d_ws + WS_V);
    prep<<<dim3(1024), dim3(256), 0, stream>>>(k, v, wsK, wsV);
    fused<<<dim3(1024), dim3(256), 0, stream>>>(q, sg, wsK, wsV, outp);
}

// Round 8
// 837.008 us; speedup vs baseline: 1.0189x; 1.0189x over previous
//
#include <hip/hip_runtime.h>

#define L_ 2048
#define H_ 8

typedef __attribute__((ext_vector_type(8))) short short8;
typedef __attribute__((ext_vector_type(4))) float f32x4;

static constexpr size_t OFF_S = 2097152;            // B*L*H*D
static constexpr size_t OFF_P = OFF_S + 67108864;   // + B*H*L*L
static constexpr size_t OFF_G = OFF_P + 67108864;

// ws layout (bytes): K tiles at 1 MB (4 MB), V tiles at 5 MB (4 MB)
static constexpr size_t WS_K = 1u << 20;
static constexpr size_t WS_V = WS_K + (4u << 20);

__device__ __forceinline__ unsigned short f2bf(float x) {
    union { float f; unsigned int u; } c; c.f = x;
    unsigned int u = c.u;
    u += 0x7fffu + ((u >> 16) & 1u);               // RNE
    return (unsigned short)(u >> 16);
}

__device__ __forceinline__ void gld_lds16(const unsigned short* g, unsigned short* l) {
    __builtin_amdgcn_global_load_lds(
        (const __attribute__((address_space(1))) void*)g,
        (__attribute__((address_space(3))) void*)l, 16, 0, 0);
}

// non-temporal stores (native clang vector types required by the builtin)
__device__ __forceinline__ void st_nt4(float* p, f32x4 v) {
    __builtin_nontemporal_store(v, reinterpret_cast<f32x4*>(p));
}
__device__ __forceinline__ void st_nt1(float* p, float v) {
    __builtin_nontemporal_store(v, p);
}

// ===== kernel 0: K -> bf16 swizzled tiles; V -> bf16 transposed swizzled tiles =====
// tile image: 64 rows x 64 bf16; element (r, chunk c) at r*64 + (c ^ (r&7))*8 shorts.
__global__ __launch_bounds__(256) void prep(
    const float* __restrict__ k, const float* __restrict__ v,
    unsigned short* __restrict__ wsK, unsigned short* __restrict__ wsV)
{
    const int tid = threadIdx.x;
    const int blk = blockIdx.x;
    __shared__ __attribute__((aligned(16))) unsigned short tr[64][72];
    if (blk < 512) {                                 // K path: (bh, t)
        const int bh = blk >> 5, t = blk & 31;
        const int b = bh >> 3, h = bh & 7;
        unsigned short* dst = wsK + (size_t)(bh * 32 + t) * 4096;
        #pragma unroll
        for (int p = 0; p < 2; ++p) {
            const int cid = tid + (p << 8);
            const int r = cid >> 3, c = cid & 7;
            const int j = (t << 6) + r;
            const float4* src = reinterpret_cast<const float4*>(
                k + (((size_t)((b * L_ + j) * H_ + h)) << 6) + (c << 3));
            float4 x0 = src[0], x1 = src[1];
            union { short8 s; unsigned short u[8]; } w;
            w.u[0]=f2bf(x0.x); w.u[1]=f2bf(x0.y); w.u[2]=f2bf(x0.z); w.u[3]=f2bf(x0.w);
            w.u[4]=f2bf(x1.x); w.u[5]=f2bf(x1.y); w.u[6]=f2bf(x1.z); w.u[7]=f2bf(x1.w);
            *reinterpret_cast<short8*>(dst + r * 64 + ((c ^ (r & 7)) << 3)) = w.s;
        }
    } else {                                         // V path: transpose via LDS
        const int vb = blk - 512;
        const int bh = vb >> 5, t = vb & 31;
        const int b = bh >> 3, h = bh & 7;
        const int col4 = (tid & 15) << 2;
        #pragma unroll
        for (int p = 0; p < 4; ++p) {
            const int r = (tid >> 4) + (p << 4);
            const int j = (t << 6) + r;
            float4 x = *reinterpret_cast<const float4*>(
                v + (((size_t)((b * L_ + j) * H_ + h)) << 6) + col4);
            tr[col4 + 0][r] = f2bf(x.x); tr[col4 + 1][r] = f2bf(x.y);
            tr[col4 + 2][r] = f2bf(x.z); tr[col4 + 3][r] = f2bf(x.w);
        }
        __syncthreads();
        unsigned short* dst = wsV + (size_t)(bh * 32 + t) * 4096;
        #pragma unroll
        for (int p = 0; p < 2; ++p) {
            const int cid = tid + (p << 8);
            const int d = cid >> 3, cj = cid & 7;
            short8 s = *reinterpret_cast<const short8*>(&tr[d][cj << 3]);
            *reinterpret_cast<short8*>(dst + d * 64 + ((cj ^ (d & 7)) << 3)) = s;
        }
    }
}

// ===== kernel 1: fused attention, QBLK=32, channel-decorrelated phase 2 =====
// Phase 1: LDS-staged QK->exp->PV (unchanged from r7).
// Phase 2: tile visit order ROTATED per block (series loop) / per wave
//          (streaming loop) so concurrent blocks' writes spread across HBM
//          pseudo-channels instead of camping on the same 8 KB-stride set.
__global__ __launch_bounds__(256, 4) void fused(
    const float* __restrict__ q, const float* __restrict__ sg,
    const unsigned short* __restrict__ wsK, const unsigned short* __restrict__ wsV,
    float* __restrict__ out)
{
    __shared__ __attribute__((aligned(16))) unsigned short Kb[2][4096];
    __shared__ __attribute__((aligned(16))) unsigned short Vb[2][4096];
    __shared__ __attribute__((aligned(16))) unsigned short Pt[32][72];
    __shared__ float l_sums[32];
    __shared__ float sA[32], sC2[32], sS[32];

    const int tid  = threadIdx.x;
    const int wv   = tid >> 6;
    const int lane = tid & 63;
    const int quad = lane >> 4;
    const int l16  = lane & 15;

    const int blk = blockIdx.x;
    const int s   = 63 - (blk >> 4);                 // heavy strips first
    const int bh  = blk & 15;
    const int b   = bh >> 3, h = bh & 7;
    const int i0  = s << 5;                          // 32-row strip

    const int ntiles = (s >> 1) + 1;
    const unsigned short* gK = wsK + ((size_t)bh * 32) * 4096;
    const unsigned short* gV = wsV + ((size_t)bh * 32) * 4096;

    #define STAGE(buf, t) do {                                              \
        const unsigned short* _sk = gK + (size_t)(t) * 4096;                \
        const unsigned short* _sv = gV + (size_t)(t) * 4096;                \
        _Pragma("unroll")                                                   \
        for (int _qq = 0; _qq < 2; ++_qq) {                                 \
            const int _off = (wv << 10) + (_qq << 9);                       \
            gld_lds16(_sk + _off + (lane << 3), &Kb[buf][_off]);            \
            gld_lds16(_sv + _off + (lane << 3), &Vb[buf][_off]);            \
        }                                                                   \
    } while (0)

    STAGE(0, 0);                                     // issue first DMA ASAP

    // sigma-derived per-row params (32 rows)
    if (tid < 32) {
        l_sums[tid] = 0.0f;
        const int i = i0 + tid;
        const float x = sg[(size_t)((b * L_ + i) * H_ + h)];
        const float sgm = 1.0f / (1.0f + __expf(-5.0f * x)) + 1e-5f;
        const float sp  = expm1f(sgm * 1.0986122886681098f);   // 3^sgm - 1
        sS[tid]  = sp;
        sA[tid]  = 0.3989422804014327f / sp;
        sC2[tid] = 0.5f / (sp * sp);
    }

    // Q A-fragments for both 16-row halves (fp32 -> bf16, once per block)
    short8 a0[2], a1[2];
    #pragma unroll
    for (int qh = 0; qh < 2; ++qh) {
        const float* qr = q + (((size_t)((b * L_ + (i0 + (qh << 4) + l16)) * H_ + h)) << 6);
        const float4* q4 = reinterpret_cast<const float4*>(qr) + quad * 2;
        float4 x0 = q4[0], x1 = q4[1];
        float4 y0 = q4[8], y1 = q4[9];
        union { short8 v8; unsigned short u[8]; } fa, fb;
        fa.u[0]=f2bf(x0.x); fa.u[1]=f2bf(x0.y); fa.u[2]=f2bf(x0.z); fa.u[3]=f2bf(x0.w);
        fa.u[4]=f2bf(x1.x); fa.u[5]=f2bf(x1.y); fa.u[6]=f2bf(x1.z); fa.u[7]=f2bf(x1.w);
        fb.u[0]=f2bf(y0.x); fb.u[1]=f2bf(y0.y); fb.u[2]=f2bf(y0.z); fb.u[3]=f2bf(y0.w);
        fb.u[4]=f2bf(y1.x); fb.u[5]=f2bf(y1.y); fb.u[6]=f2bf(y1.z); fb.u[7]=f2bf(y1.w);
        a0[qh] = fa.v8; a1[qh] = fb.v8;
    }

    f32x4 oacc[2] = {{0.f,0.f,0.f,0.f}, {0.f,0.f,0.f,0.f}};
    float lpart[2][4] = {{0.f,0.f,0.f,0.f}, {0.f,0.f,0.f,0.f}};
    const int r = (wv << 4) + l16;                   // K/V tile row this lane fragments

    for (int t = 0; t < ntiles; ++t) {
        const int p = t & 1;
        __syncthreads();                             // buf[p] staged; prev iter fully done
        if (t + 1 < ntiles) STAGE(1 - p, t + 1);     // overlap next DMA with compute
        short8 b0 = *reinterpret_cast<const short8*>(&Kb[p][r * 64 + ((quad ^ (r & 7)) << 3)]);
        short8 b1 = *reinterpret_cast<const short8*>(&Kb[p][r * 64 + (((quad + 4) ^ (r & 7)) << 3)]);
        const int j = (t << 6) + r;
        #pragma unroll
        for (int qh = 0; qh < 2; ++qh) {
            f32x4 c4 = {0.f, 0.f, 0.f, 0.f};
            c4 = __builtin_amdgcn_mfma_f32_16x16x32_bf16(a0[qh], b0, c4, 0, 0, 0);
            c4 = __builtin_amdgcn_mfma_f32_16x16x32_bf16(a1[qh], b1, c4, 0, 0, 0);
            #pragma unroll
            for (int rr = 0; rr < 4; ++rr) {
                const int i = i0 + (qh << 4) + (quad << 2) + rr;
                float pv = (j <= i) ? __expf(c4[rr] * 0.125f - 8.0f) : 0.0f;
                lpart[qh][rr] += pv;
                Pt[(qh << 4) + (quad << 2) + rr][r] = f2bf(pv);
            }
        }
        __syncthreads();
        short8 vb0 = *reinterpret_cast<const short8*>(&Vb[p][r * 64 + ((quad ^ (r & 7)) << 3)]);
        short8 vb1 = *reinterpret_cast<const short8*>(&Vb[p][r * 64 + (((quad + 4) ^ (r & 7)) << 3)]);
        #pragma unroll
        for (int qh = 0; qh < 2; ++qh) {
            short8 pa0 = *reinterpret_cast<const short8*>(&Pt[(qh << 4) + l16][quad << 3]);
            short8 pa1 = *reinterpret_cast<const short8*>(&Pt[(qh << 4) + l16][32 + (quad << 3)]);
            oacc[qh] = __builtin_amdgcn_mfma_f32_16x16x32_bf16(pa0, vb0, oacc[qh], 0, 0, 0);
            oacc[qh] = __builtin_amdgcn_mfma_f32_16x16x32_bf16(pa1, vb1, oacc[qh], 0, 0, 0);
        }
    }
    #undef STAGE

    #pragma unroll
    for (int qh = 0; qh < 2; ++qh)
    #pragma unroll
    for (int rr = 0; rr < 4; ++rr) {
        float x = lpart[qh][rr];
        x += __shfl_xor(x, 1); x += __shfl_xor(x, 2);
        x += __shfl_xor(x, 4); x += __shfl_xor(x, 8);
        if (l16 == 0) atomicAdd(&l_sums[(qh << 4) + (quad << 2) + rr], x);
    }
    __syncthreads();                                 // l_sums final; phase-1 LDS reads done

    float inv[2][4];
    #pragma unroll
    for (int qh = 0; qh < 2; ++qh)
    #pragma unroll
    for (int rr = 0; rr < 4; ++rr) {
        inv[qh][rr] = 1.0f / l_sums[(qh << 4) + (quad << 2) + rr];
        const int i = i0 + (qh << 4) + (quad << 2) + rr;
        st_nt1(out + (((size_t)((b * L_ + i) * H_ + h)) << 6) + (wv << 4) + l16,
               oacc[qh][rr] * inv[qh][rr]);
    }

    // ===== phase 2: streaming writeback, rotated visit order =====
    float* outS = out + OFF_S;
    float* outP = out + OFF_P;
    float* outG = out + OFF_G;
    float* PsA = reinterpret_cast<float*>(&Kb[0][0]); // 32 x 68 f32 = 8704 B
    float* PsB = reinterpret_cast<float*>(&Vb[0][0]);

    // consumer lane map: pass ps covers rows ps*16 + wv*4 + quad, cols l16*4
    const int rc0  = (wv << 2) + quad;
    const int colc = l16 << 2;
    float Ac[2], C2c[2], fic[2];
    f32x4 svc[2];
    size_t rowbase[2];
    #pragma unroll
    for (int ps = 0; ps < 2; ++ps) {
        const int row = rc0 + (ps << 4);
        Ac[ps]  = sA[row]; C2c[ps] = sC2[row];
        const float Sv = sS[row];
        svc[ps] = (f32x4){Sv, Sv, Sv, Sv};
        fic[ps] = (float)(i0 + row);
        rowbase[ps] = ((size_t)(bh * L_ + i0 + row)) << 11;
    }

    // producer K-fragment offsets inside a tile (shorts) — same r as phase 1
    const int off0 = r * 64 + ((quad ^ (r & 7)) << 3);
    const int off1 = r * 64 + (((quad + 4) ^ (r & 7)) << 3);

    // per-block rotation of the series tile order (HBM channel decorrelation)
    const int rot = (bh * 5 + s * 3 + 1) % ntiles;   // block-uniform
    int tv = rot;                                    // visit: rot, rot+1, ..., wrap

    short8 kb0 = *reinterpret_cast<const short8*>(gK + ((size_t)tv << 12) + off0);
    short8 kb1 = *reinterpret_cast<const short8*>(gK + ((size_t)tv << 12) + off1);
    for (int t = 0; t < ntiles; ++t) {
        int tvn = tv + 1; if (tvn >= ntiles) tvn = 0;
        short8 kn0 = kb0, kn1 = kb1;
        if (t + 1 < ntiles) {                        // reg prefetch: next tile in sequence
            const unsigned short* kp = gK + ((size_t)tvn << 12);
            kn0 = *reinterpret_cast<const short8*>(kp + off0);
            kn1 = *reinterpret_cast<const short8*>(kp + off1);
        }
        float* Ps = (t & 1) ? PsB : PsA;
        const int j = (tv << 6) + r;
        #pragma unroll
        for (int qh = 0; qh < 2; ++qh) {
            f32x4 c4 = {0.f, 0.f, 0.f, 0.f};
            c4 = __builtin_amdgcn_mfma_f32_16x16x32_bf16(a0[qh], kb0, c4, 0, 0, 0);
            c4 = __builtin_amdgcn_mfma_f32_16x16x32_bf16(a1[qh], kb1, c4, 0, 0, 0);
            #pragma unroll
            for (int rr = 0; rr < 4; ++rr) {
                const int i = i0 + (qh << 4) + (quad << 2) + rr;
                const float pv = (j <= i) ? __expf(c4[rr] * 0.125f - 8.0f) * inv[qh][rr] : 0.0f;
                Ps[((qh << 4) + (quad << 2) + rr) * 68 + r] = pv;
            }
        }
        asm volatile("s_waitcnt lgkmcnt(0)" ::: "memory");
        __builtin_amdgcn_sched_barrier(0);
        __builtin_amdgcn_s_barrier();                // P tile visible; single barrier/iter
        #pragma unroll
        for (int ps = 0; ps < 2; ++ps) {
            const f32x4 se = *reinterpret_cast<const f32x4*>(&Ps[(rc0 + (ps << 4)) * 68 + colc]);
            const int c = (tv << 6) + colc;
            const float d0 = fic[ps] - (float)c;
            const float d1 = d0 - 1.f, d2 = d0 - 2.f, d3 = d0 - 3.f;
            f32x4 pr;
            pr.x = Ac[ps] * __expf(-d0 * d0 * C2c[ps]);
            pr.y = Ac[ps] * __expf(-d1 * d1 * C2c[ps]);
            pr.z = Ac[ps] * __expf(-d2 * d2 * C2c[ps]);
            pr.w = Ac[ps] * __expf(-d3 * d3 * C2c[ps]);
            st_nt4(outS + rowbase[ps] + c, se);
            st_nt4(outP + rowbase[ps] + c, pr);
            st_nt4(outG + rowbase[ps] + c, svc[ps]);
        }
        kb0 = kn0; kb1 = kn1;
        tv = tvn;
    }
    // pure streaming region: per-wave rotated order (no barriers here)
    const int span = 32 - ntiles;
    const int rotw = span ? ((bh + s * 3 + wv * 7) % span) : 0;
    const f32x4 z4 = {0.f, 0.f, 0.f, 0.f};
    for (int tz = 0; tz < span; ++tz) {
        int u = tz + rotw; if (u >= span) u -= span;
        const int tu = ntiles + u;
        #pragma unroll
        for (int ps = 0; ps < 2; ++ps) {
            const int c = (tu << 6) + colc;
            const float d0 = fic[ps] - (float)c;
            const float d1 = d0 - 1.f, d2 = d0 - 2.f, d3 = d0 - 3.f;
            f32x4 pr;
            pr.x = Ac[ps] * __expf(-d0 * d0 * C2c[ps]);
            pr.y = Ac[ps] * __expf(-d1 * d1 * C2c[ps]);
            pr.z = Ac[ps] * __expf(-d2 * d2 * C2c[ps]);
            pr.w = Ac[ps] * __expf(-d3 * d3 * C2c[ps]);
            st_nt4(outS + rowbase[ps] + c, z4);
            st_nt4(outP + rowbase[ps] + c, pr);
            st_nt4(outG + rowbase[ps] + c, svc[ps]);
        }
    }
}

extern "C" void kernel_launch(void* const* d_in, const int* in_sizes, int n_in,
                              void* d_out, int out_size, void* d_ws, size_t ws_size,
                              hipStream_t stream) {
    const float* q  = (const float*)d_in[0];
    const float* k  = (const float*)d_in[1];
    const float* v  = (const float*)d_in[2];
    const float* sg = (const float*)d_in[3];
    float* outp = (float*)d_out;
    unsigned short* wsK = (unsigned short*)((char*)d_ws + WS_K);
    unsigned short* wsV = (unsigned short*)((char*)d_ws + WS_V);
    prep<<<dim3(1024), dim3(256), 0, stream>>>(k, v, wsK, wsV);
    fused<<<dim3(1024), dim3(256), 0, stream>>>(q, sg, wsK, wsV, outp);
}

// Round 9
// 824.790 us; speedup vs baseline: 1.0340x; 1.0148x over previous
//
#include <hip/hip_runtime.h>

#define L_ 2048
#define H_ 8

typedef __attribute__((ext_vector_type(8))) short short8;
typedef __attribute__((ext_vector_type(4))) float f32x4;

static constexpr size_t OFF_S = 2097152;            // B*L*H*D
static constexpr size_t OFF_P = OFF_S + 67108864;   // + B*H*L*L
static constexpr size_t OFF_G = OFF_P + 67108864;

// ws layout (bytes): K tiles at 1 MB (4 MB), V tiles at 5 MB (4 MB)
static constexpr size_t WS_K = 1u << 20;
static constexpr size_t WS_V = WS_K + (4u << 20);

__device__ __forceinline__ unsigned short f2bf(float x) {
    union { float f; unsigned int u; } c; c.f = x;
    unsigned int u = c.u;
    u += 0x7fffu + ((u >> 16) & 1u);               // RNE
    return (unsigned short)(u >> 16);
}

__device__ __forceinline__ void gld_lds16(const unsigned short* g, unsigned short* l) {
    __builtin_amdgcn_global_load_lds(
        (const __attribute__((address_space(1))) void*)g,
        (__attribute__((address_space(3))) void*)l, 16, 0, 0);
}

// non-temporal stores (native clang vector types required by the builtin)
__device__ __forceinline__ void st_nt4(float* p, f32x4 v) {
    __builtin_nontemporal_store(v, reinterpret_cast<f32x4*>(p));
}
__device__ __forceinline__ void st_nt1(float* p, float v) {
    __builtin_nontemporal_store(v, p);
}

// ===== kernel 0: K -> bf16 swizzled tiles; V -> bf16 transposed swizzled tiles =====
__global__ __launch_bounds__(256) void prep(
    const float* __restrict__ k, const float* __restrict__ v,
    unsigned short* __restrict__ wsK, unsigned short* __restrict__ wsV)
{
    const int tid = threadIdx.x;
    const int blk = blockIdx.x;
    __shared__ __attribute__((aligned(16))) unsigned short tr[64][72];
    if (blk < 512) {                                 // K path: (bh, t)
        const int bh = blk >> 5, t = blk & 31;
        const int b = bh >> 3, h = bh & 7;
        unsigned short* dst = wsK + (size_t)(bh * 32 + t) * 4096;
        #pragma unroll
        for (int p = 0; p < 2; ++p) {
            const int cid = tid + (p << 8);
            const int r = cid >> 3, c = cid & 7;
            const int j = (t << 6) + r;
            const float4* src = reinterpret_cast<const float4*>(
                k + (((size_t)((b * L_ + j) * H_ + h)) << 6) + (c << 3));
            float4 x0 = src[0], x1 = src[1];
            union { short8 s; unsigned short u[8]; } w;
            w.u[0]=f2bf(x0.x); w.u[1]=f2bf(x0.y); w.u[2]=f2bf(x0.z); w.u[3]=f2bf(x0.w);
            w.u[4]=f2bf(x1.x); w.u[5]=f2bf(x1.y); w.u[6]=f2bf(x1.z); w.u[7]=f2bf(x1.w);
            *reinterpret_cast<short8*>(dst + r * 64 + ((c ^ (r & 7)) << 3)) = w.s;
        }
    } else {                                         // V path: transpose via LDS
        const int vb = blk - 512;
        const int bh = vb >> 5, t = vb & 31;
        const int b = bh >> 3, h = bh & 7;
        const int col4 = (tid & 15) << 2;
        #pragma unroll
        for (int p = 0; p < 4; ++p) {
            const int r = (tid >> 4) + (p << 4);
            const int j = (t << 6) + r;
            float4 x = *reinterpret_cast<const float4*>(
                v + (((size_t)((b * L_ + j) * H_ + h)) << 6) + col4);
            tr[col4 + 0][r] = f2bf(x.x); tr[col4 + 1][r] = f2bf(x.y);
            tr[col4 + 2][r] = f2bf(x.z); tr[col4 + 3][r] = f2bf(x.w);
        }
        __syncthreads();
        unsigned short* dst = wsV + (size_t)(bh * 32 + t) * 4096;
        #pragma unroll
        for (int p = 0; p < 2; ++p) {
            const int cid = tid + (p << 8);
            const int d = cid >> 3, cj = cid & 7;
            short8 s = *reinterpret_cast<const short8*>(&tr[d][cj << 3]);
            *reinterpret_cast<short8*>(dst + d * 64 + ((cj ^ (d & 7)) << 3)) = s;
        }
    }
}

// ===== kernel 1: fused attention, QBLK=32; phase 2 = fill-shaped stores =====
// Phase 1: LDS-staged QK->exp->PV (unchanged).
// Phase 2a: series lower-triangle in GROUPS of 4 tiles; normalized P collected
//           in a 32x256 f32 LDS image (Kb=rows0-15, Vb=rows16-31); each wave
//           dumps 8 rows as 1 KB contiguous nt stores. 2 barriers per group.
// Phase 2b: row sweep — prior + sigma (all cols) + series zeros (cols beyond
//           the group region) as 1 KB contiguous nt stores, rotated chunk order.
__global__ __launch_bounds__(256, 4) void fused(
    const float* __restrict__ q, const float* __restrict__ sg,
    const unsigned short* __restrict__ wsK, const unsigned short* __restrict__ wsV,
    float* __restrict__ out)
{
    __shared__ __attribute__((aligned(16))) unsigned short Kb[2][4096];
    __shared__ __attribute__((aligned(16))) unsigned short Vb[2][4096];
    __shared__ __attribute__((aligned(16))) unsigned short Pt[32][72];
    __shared__ float l_sums[32];
    __shared__ float sA[32], sC2[32], sS[32];

    const int tid  = threadIdx.x;
    const int wv   = tid >> 6;
    const int lane = tid & 63;
    const int quad = lane >> 4;
    const int l16  = lane & 15;

    const int blk = blockIdx.x;
    const int s   = 63 - (blk >> 4);                 // heavy strips first
    const int bh  = blk & 15;
    const int b   = bh >> 3, h = bh & 7;
    const int i0  = s << 5;                          // 32-row strip

    const int ntiles = (s >> 1) + 1;
    const unsigned short* gK = wsK + ((size_t)bh * 32) * 4096;
    const unsigned short* gV = wsV + ((size_t)bh * 32) * 4096;

    #define STAGE(buf, t) do {                                              \
        const unsigned short* _sk = gK + (size_t)(t) * 4096;                \
        const unsigned short* _sv = gV + (size_t)(t) * 4096;                \
        _Pragma("unroll")                                                   \
        for (int _qq = 0; _qq < 2; ++_qq) {                                 \
            const int _off = (wv << 10) + (_qq << 9);                       \
            gld_lds16(_sk + _off + (lane << 3), &Kb[buf][_off]);            \
            gld_lds16(_sv + _off + (lane << 3), &Vb[buf][_off]);            \
        }                                                                   \
    } while (0)

    STAGE(0, 0);                                     // issue first DMA ASAP

    // sigma-derived per-row params (32 rows)
    if (tid < 32) {
        l_sums[tid] = 0.0f;
        const int i = i0 + tid;
        const float x = sg[(size_t)((b * L_ + i) * H_ + h)];
        const float sgm = 1.0f / (1.0f + __expf(-5.0f * x)) + 1e-5f;
        const float sp  = expm1f(sgm * 1.0986122886681098f);   // 3^sgm - 1
        sS[tid]  = sp;
        sA[tid]  = 0.3989422804014327f / sp;
        sC2[tid] = 0.5f / (sp * sp);
    }

    // Q A-fragments for both 16-row halves (fp32 -> bf16, once per block)
    short8 a0[2], a1[2];
    #pragma unroll
    for (int qh = 0; qh < 2; ++qh) {
        const float* qr = q + (((size_t)((b * L_ + (i0 + (qh << 4) + l16)) * H_ + h)) << 6);
        const float4* q4 = reinterpret_cast<const float4*>(qr) + quad * 2;
        float4 x0 = q4[0], x1 = q4[1];
        float4 y0 = q4[8], y1 = q4[9];
        union { short8 v8; unsigned short u[8]; } fa, fb;
        fa.u[0]=f2bf(x0.x); fa.u[1]=f2bf(x0.y); fa.u[2]=f2bf(x0.z); fa.u[3]=f2bf(x0.w);
        fa.u[4]=f2bf(x1.x); fa.u[5]=f2bf(x1.y); fa.u[6]=f2bf(x1.z); fa.u[7]=f2bf(x1.w);
        fb.u[0]=f2bf(y0.x); fb.u[1]=f2bf(y0.y); fb.u[2]=f2bf(y0.z); fb.u[3]=f2bf(y0.w);
        fb.u[4]=f2bf(y1.x); fb.u[5]=f2bf(y1.y); fb.u[6]=f2bf(y1.z); fb.u[7]=f2bf(y1.w);
        a0[qh] = fa.v8; a1[qh] = fb.v8;
    }

    f32x4 oacc[2] = {{0.f,0.f,0.f,0.f}, {0.f,0.f,0.f,0.f}};
    float lpart[2][4] = {{0.f,0.f,0.f,0.f}, {0.f,0.f,0.f,0.f}};
    const int r = (wv << 4) + l16;                   // K/V tile row this lane fragments

    for (int t = 0; t < ntiles; ++t) {
        const int p = t & 1;
        __syncthreads();                             // buf[p] staged; prev iter fully done
        if (t + 1 < ntiles) STAGE(1 - p, t + 1);     // overlap next DMA with compute
        short8 b0 = *reinterpret_cast<const short8*>(&Kb[p][r * 64 + ((quad ^ (r & 7)) << 3)]);
        short8 b1 = *reinterpret_cast<const short8*>(&Kb[p][r * 64 + (((quad + 4) ^ (r & 7)) << 3)]);
        const int j = (t << 6) + r;
        #pragma unroll
        for (int qh = 0; qh < 2; ++qh) {
            f32x4 c4 = {0.f, 0.f, 0.f, 0.f};
            c4 = __builtin_amdgcn_mfma_f32_16x16x32_bf16(a0[qh], b0, c4, 0, 0, 0);
            c4 = __builtin_amdgcn_mfma_f32_16x16x32_bf16(a1[qh], b1, c4, 0, 0, 0);
            #pragma unroll
            for (int rr = 0; rr < 4; ++rr) {
                const int i = i0 + (qh << 4) + (quad << 2) + rr;
                float pv = (j <= i) ? __expf(c4[rr] * 0.125f - 8.0f) : 0.0f;
                lpart[qh][rr] += pv;
                Pt[(qh << 4) + (quad << 2) + rr][r] = f2bf(pv);
            }
        }
        __syncthreads();
        short8 vb0 = *reinterpret_cast<const short8*>(&Vb[p][r * 64 + ((quad ^ (r & 7)) << 3)]);
        short8 vb1 = *reinterpret_cast<const short8*>(&Vb[p][r * 64 + (((quad + 4) ^ (r & 7)) << 3)]);
        #pragma unroll
        for (int qh = 0; qh < 2; ++qh) {
            short8 pa0 = *reinterpret_cast<const short8*>(&Pt[(qh << 4) + l16][quad << 3]);
            short8 pa1 = *reinterpret_cast<const short8*>(&Pt[(qh << 4) + l16][32 + (quad << 3)]);
            oacc[qh] = __builtin_amdgcn_mfma_f32_16x16x32_bf16(pa0, vb0, oacc[qh], 0, 0, 0);
            oacc[qh] = __builtin_amdgcn_mfma_f32_16x16x32_bf16(pa1, vb1, oacc[qh], 0, 0, 0);
        }
    }
    #undef STAGE

    #pragma unroll
    for (int qh = 0; qh < 2; ++qh)
    #pragma unroll
    for (int rr = 0; rr < 4; ++rr) {
        float x = lpart[qh][rr];
        x += __shfl_xor(x, 1); x += __shfl_xor(x, 2);
        x += __shfl_xor(x, 4); x += __shfl_xor(x, 8);
        if (l16 == 0) atomicAdd(&l_sums[(qh << 4) + (quad << 2) + rr], x);
    }
    __syncthreads();                                 // l_sums final; all DMAs drained

    float inv[2][4];
    #pragma unroll
    for (int qh = 0; qh < 2; ++qh)
    #pragma unroll
    for (int rr = 0; rr < 4; ++rr) {
        inv[qh][rr] = 1.0f / l_sums[(qh << 4) + (quad << 2) + rr];
        const int i = i0 + (qh << 4) + (quad << 2) + rr;
        st_nt1(out + (((size_t)((b * L_ + i) * H_ + h)) << 6) + (wv << 4) + l16,
               oacc[qh][rr] * inv[qh][rr]);
    }

    // ===== phase 2a: series lower region, groups of 4 tiles, 1 KB row dumps =====
    float* outS = out + OFF_S;
    float* outP = out + OFF_P;
    float* outG = out + OFF_G;
    float* PsLo = reinterpret_cast<float*>(&Kb[0][0]); // rows 0-15, stride 256 f32
    float* PsHi = reinterpret_cast<float*>(&Vb[0][0]); // rows 16-31

    const int off0 = r * 64 + ((quad ^ (r & 7)) << 3);
    const int off1 = r * 64 + (((quad + 4) ^ (r & 7)) << 3);

    const int ngl  = (ntiles + 3) >> 2;              // groups containing real tiles
    const int grot = (bh + 3 * s) % ngl;

    for (int g = 0; g < ngl; ++g) {
        int gv = g + grot; if (gv >= ngl) gv -= ngl;
        short8 kf0[4], kf1[4];
        #pragma unroll
        for (int tl = 0; tl < 4; ++tl) {             // issue group's K-frag loads
            const int t = (gv << 2) + tl;
            if (t < ntiles) {
                const unsigned short* kp = gK + ((size_t)t << 12);
                kf0[tl] = *reinterpret_cast<const short8*>(kp + off0);
                kf1[tl] = *reinterpret_cast<const short8*>(kp + off1);
            }
        }
        #pragma unroll
        for (int tl = 0; tl < 4; ++tl) {
            const int t = (gv << 2) + tl;
            const int j = (t << 6) + r;
            if (t < ntiles) {
                #pragma unroll
                for (int qh = 0; qh < 2; ++qh) {
                    f32x4 c4 = {0.f, 0.f, 0.f, 0.f};
                    c4 = __builtin_amdgcn_mfma_f32_16x16x32_bf16(a0[qh], kf0[tl], c4, 0, 0, 0);
                    c4 = __builtin_amdgcn_mfma_f32_16x16x32_bf16(a1[qh], kf1[tl], c4, 0, 0, 0);
                    float* Pq = qh ? PsHi : PsLo;
                    #pragma unroll
                    for (int rr = 0; rr < 4; ++rr) {
                        const int i = i0 + (qh << 4) + (quad << 2) + rr;
                        const float pv = (j <= i) ? __expf(c4[rr] * 0.125f - 8.0f) * inv[qh][rr] : 0.0f;
                        Pq[(((quad << 2) + rr) << 8) + (tl << 6) + r] = pv;
                    }
                }
            } else {                                 // masked tiles in boundary group
                #pragma unroll
                for (int qh = 0; qh < 2; ++qh) {
                    float* Pq = qh ? PsHi : PsLo;
                    #pragma unroll
                    for (int rr = 0; rr < 4; ++rr)
                        Pq[(((quad << 2) + rr) << 8) + (tl << 6) + r] = 0.0f;
                }
            }
        }
        asm volatile("s_waitcnt lgkmcnt(0)" ::: "memory");
        __builtin_amdgcn_sched_barrier(0);
        __builtin_amdgcn_s_barrier();                // P image complete
        float* Pw = (wv < 2) ? PsLo : PsHi;
        const int rbase = (wv & 1) << 3;             // row-in-buffer base
        #pragma unroll
        for (int kk = 0; kk < 8; ++kk) {
            const int row = (wv << 3) + kk;          // block row 0..31
            const f32x4 se = *reinterpret_cast<const f32x4*>(&Pw[((rbase + kk) << 8) + (lane << 2)]);
            st_nt4(outS + (((size_t)(bh * L_ + i0 + row)) << 11) + (gv << 8) + (lane << 2), se);
        }
        __builtin_amdgcn_s_barrier();                // WAR: dumps done before next writes
    }

    // ===== phase 2b: row sweep — prior + sigma + upper series zeros, 1 KB stores =====
    const f32x4 z4 = {0.f, 0.f, 0.f, 0.f};
    #pragma unroll 1
    for (int kk = 0; kk < 8; ++kk) {
        const int row = (wv << 3) + kk;
        const float Arow = sA[row], C2r = sC2[row], Sv = sS[row];
        const f32x4 svr = {Sv, Sv, Sv, Sv};
        const float fi = (float)(i0 + row);
        const size_t rb = ((size_t)(bh * L_ + i0 + row)) << 11;
        const int c0 = (bh + s + wv * 3 + kk) & 7;   // rotated chunk start
        #pragma unroll 1
        for (int cc = 0; cc < 8; ++cc) {
            int ch = cc + c0; if (ch >= 8) ch -= 8;
            const int c = (ch << 8) + (lane << 2);
            const float d0 = fi - (float)c;
            const float d1 = d0 - 1.f, d2 = d0 - 2.f, d3 = d0 - 3.f;
            f32x4 pr;
            pr.x = Arow * __expf(-d0 * d0 * C2r);
            pr.y = Arow * __expf(-d1 * d1 * C2r);
            pr.z = Arow * __expf(-d2 * d2 * C2r);
            pr.w = Arow * __expf(-d3 * d3 * C2r);
            st_nt4(outP + rb + c, pr);
            st_nt4(outG + rb + c, svr);
            if (ch >= ngl) st_nt4(outS + rb + c, z4);
        }
    }
}

extern "C" void kernel_launch(void* const* d_in, const int* in_sizes, int n_in,
                              void* d_out, int out_size, void* d_ws, size_t ws_size,
                              hipStream_t stream) {
    const float* q  = (const float*)d_in[0];
    const float* k  = (const float*)d_in[1];
    const float* v  = (const float*)d_in[2];
    const float* sg = (const float*)d_in[3];
    float* outp = (float*)d_out;
    unsigned short* wsK = (unsigned short*)((char*)d_ws + WS_K);
    unsigned short* wsV = (unsigned short*)((char*)d_ws + WS_V);
    prep<<<dim3(1024), dim3(256), 0, stream>>>(k, v, wsK, wsV);
    fused<<<dim3(1024), dim3(256), 0, stream>>>(q, sg, wsK, wsV, outp);
}